// Round 15
// baseline (31.237 us; speedup 1.0000x reference)
//
#include <hip/hip_runtime.h>
#include <cstdint>
#include <cmath>

#define NN   4096
#define DXX  128
#define DD   64
#define KK   256
#define HH   256
#define DIN  192
#define ROWS 16
#define NT   1024
#define GRID (NN/ROWS)   // 256 blocks, 1 per CU, 16 waves -> 4 waves/SIMD

typedef __attribute__((ext_vector_type(8))) short short8;
typedef __attribute__((ext_vector_type(4))) float f32x4;
#define MFMA __builtin_amdgcn_mfma_f32_16x16x32_bf16

// ---- packed-weight offsets in d_ws (ushort units) ----
#define OW1 0          // 3 terms x 16ct x 6ks x 512
#define OW2 147456     // 3 x 16 x 8 x 512
#define OW3 344064     // 3 x 4  x 8 x 512
#define OCT 393216     // 3 x 16 x 2 x 512
#define OCN 442368     // 256 f32 (codebook row norms)

// ---- LDS strides ----
#define SW  264        // act row stride (ushorts)
#define SG  72         // gt-split row stride (ushorts)
#define SSP 260        // score row stride (floats)
#define SSG 68         // sgt row stride (floats)

__device__ __forceinline__ unsigned short f2bf(float x){
  uint32_t u = __float_as_uint(x);
  return (unsigned short)((u + 0x7fffu + ((u>>16)&1u)) >> 16);
}
__device__ __forceinline__ float bf2f(unsigned short b){
  return __uint_as_float(((uint32_t)b)<<16);
}
__device__ __forceinline__ void split3(float x, unsigned short& h, unsigned short& m, unsigned short& l){
  h = f2bf(x); float r1 = x - bf2f(h);
  m = f2bf(r1); float r2 = r1 - bf2f(m);
  l = f2bf(r2);
}

// ---------------- Threefry-2x32 (20 rounds), exact JAX semantics ----------------
__device__ __forceinline__ uint32_t rotl32(uint32_t v, uint32_t r){ return (v<<r)|(v>>(32u-r)); }
__device__ __forceinline__ void tf2x32(uint32_t k0, uint32_t k1,
                                       uint32_t x0, uint32_t x1,
                                       uint32_t& o0, uint32_t& o1){
  const uint32_t ks0=k0, ks1=k1, ks2 = k0 ^ k1 ^ 0x1BD11BDAu;
  x0 += ks0; x1 += ks1;
  x0+=x1; x1=rotl32(x1,13); x1^=x0;
  x0+=x1; x1=rotl32(x1,15); x1^=x0;
  x0+=x1; x1=rotl32(x1,26); x1^=x0;
  x0+=x1; x1=rotl32(x1, 6); x1^=x0;
  x0+=ks1; x1+=ks2+1u;
  x0+=x1; x1=rotl32(x1,17); x1^=x0;
  x0+=x1; x1=rotl32(x1,29); x1^=x0;
  x0+=x1; x1=rotl32(x1,16); x1^=x0;
  x0+=x1; x1=rotl32(x1,24); x1^=x0;
  x0+=ks2; x1+=ks0+2u;
  x0+=x1; x1=rotl32(x1,13); x1^=x0;
  x0+=x1; x1=rotl32(x1,15); x1^=x0;
  x0+=x1; x1=rotl32(x1,26); x1^=x0;
  x0+=x1; x1=rotl32(x1, 6); x1^=x0;
  x0+=ks0; x1+=ks1+3u;
  x0+=x1; x1=rotl32(x1,17); x1^=x0;
  x0+=x1; x1=rotl32(x1,29); x1^=x0;
  x0+=x1; x1=rotl32(x1,16); x1^=x0;
  x0+=x1; x1=rotl32(x1,24); x1^=x0;
  x0+=ks1; x1+=ks2+4u;
  x0+=x1; x1=rotl32(x1,13); x1^=x0;
  x0+=x1; x1=rotl32(x1,15); x1^=x0;
  x0+=x1; x1=rotl32(x1,26); x1^=x0;
  x0+=x1; x1=rotl32(x1, 6); x1^=x0;
  x0+=ks2; x1+=ks0+5u;
  o0=x0; o1=x1;
}
__device__ __forceinline__ float gumbel_of(uint32_t ka0, uint32_t ka1, uint32_t idx){
  uint32_t o0,o1; tf2x32(ka0,ka1,0u,idx,o0,o1);
  const uint32_t bits = o0 ^ o1;
  const float TINY = 1.17549435e-38f;
  const float f = __uint_as_float((bits>>9) | 0x3F800000u) - 1.0f;
  const float u = fmaxf(TINY, f + TINY);
  return -logf(-logf(u));
}

// ---------------- prep v3: 73 fine blocks; coalesced -> LDS -> short8 ----------------
// blocks: 0-23 W1(ks,cg) | 24-55 W2(ks,cg) | 56-63 W3(ks) | 64-71 CT(ks,cg) | 72 norms
__global__ __launch_bounds__(256) void k_prep(const float* __restrict__ W1,
    const float* __restrict__ W2, const float* __restrict__ W3,
    const float* __restrict__ Cg, unsigned short* __restrict__ ws){
  const int b = blockIdx.x, t = threadIdx.x;
  __shared__ __align__(16) float lds[2112];   // W: 32*65=2080; CT: 64*33=2112
  if (b < 64){
    const float* W; int N, KS, NTt, ks, cg; size_t base;
    if (b < 24){ W=W1; N=256; KS=6; NTt=16; base=OW1; ks=b/4;      cg=b&3; }
    else if (b < 56){ W=W2; N=256; KS=8; NTt=16; base=OW2; ks=(b-24)/4; cg=(b-24)&3; }
    else { W=W3; N=64; KS=8; NTt=4; base=OW3; ks=b-56; cg=0; }
    const int k0 = ks*32, cb = cg*64;
    // load 32 rows x 64 cols (coalesced float4)
    for (int idx=t; idx<512; idx+=256){
      int row = idx>>4, c4 = idx&15;
      float4 v = *(const float4*)&W[(size_t)(k0+row)*N + cb + c4*4];
      float* d = &lds[row*65 + c4*4];
      d[0]=v.x; d[1]=v.y; d[2]=v.z; d[3]=v.w;
    }
    __syncthreads();
    const size_t term = (size_t)NTt*KS*512;
    const int lane = t&63, ctl = t>>6;
    const int ct = cg*4 + ctl;
    const int cl = ctl*16 + (lane&15);
    const int kofs = 8*(lane>>4);
    short8 hv,mv,lv;
    #pragma unroll
    for (int j=0;j<8;++j){
      float w = lds[(kofs+j)*65 + cl];
      unsigned short h,m,lo; split3(w,h,m,lo);
      hv[j]=(short)h; mv[j]=(short)m; lv[j]=(short)lo;
    }
    const size_t o = base + ((size_t)ct*KS+ks)*512 + (size_t)lane*8;
    *(short8*)&ws[o]=hv; *(short8*)&ws[o+term]=mv; *(short8*)&ws[o+2*term]=lv;
  } else if (b < 72){
    const int ks = (b-64)/4, cg = (b-64)&3;
    const int d0 = ks*32, code0 = cg*64;
    for (int idx=t; idx<512; idx+=256){       // 64 codes x 8 float4
      int code = idx>>3, d4 = idx&7;
      float4 v = *(const float4*)&Cg[(size_t)(code0+code)*64 + d0 + d4*4];
      float* d = &lds[code*33 + d4*4];
      d[0]=v.x; d[1]=v.y; d[2]=v.z; d[3]=v.w;
    }
    __syncthreads();
    const size_t term = (size_t)16*2*512;
    const int lane = t&63, ctl = t>>6;
    const int ct = cg*4 + ctl;
    const int cl = ctl*16 + (lane&15);
    const int kofs = 8*(lane>>4);
    short8 hv,mv,lv;
    #pragma unroll
    for (int j=0;j<8;++j){
      float w = lds[cl*33 + kofs + j];
      unsigned short h,m,lo; split3(w,h,m,lo);
      hv[j]=(short)h; mv[j]=(short)m; lv[j]=(short)lo;
    }
    const size_t o = OCT + ((size_t)ct*2+ks)*512 + (size_t)lane*8;
    *(short8*)&ws[o]=hv; *(short8*)&ws[o+term]=mv; *(short8*)&ws[o+2*term]=lv;
  } else {
    const int c = t;
    float s=0.f;
    #pragma unroll 8
    for (int d=0; d<64; ++d){ float v=Cg[(size_t)c*64+d]; s += v*v; }
    ((float*)(ws+OCN))[c] = s;
  }
}

// ---------------- fused main kernel: 16 waves, 1 ct/wave, 6 indep accumulators ----
__global__ __launch_bounds__(NT,4) void k_fused(
    const float* __restrict__ z, const float* __restrict__ ks,
    const float* __restrict__ xt, const void* __restrict__ maskp,
    const float* __restrict__ tr, const float* __restrict__ spk,
    const float* __restrict__ b1, const float* __restrict__ b2,
    const float* __restrict__ b3, const float* __restrict__ Cg,
    const int* __restrict__ seedp, const unsigned short* __restrict__ pws,
    float* __restrict__ out_z, float* __restrict__ out_kl,
    float* __restrict__ out_dkl, float* __restrict__ out_qk)
{
  const int t    = threadIdx.x;
  const int lane = t & 63;
  const int wv   = t >> 6;            // wave 0..15
  const int lr   = lane & 15;
  const int lg   = lane >> 4;
  const int n0   = blockIdx.x * ROWS;
  const int nw   = n0 + wv;           // finalize: wave wv owns row nw

  __shared__ __align__(16) char smem[61952];
  unsigned short* Ah = (unsigned short*)smem;            // bufA: layer input / h2
  unsigned short* Am = Ah + 16*SW;
  unsigned short* Al = Am + 16*SW;
  unsigned short* Bh = (unsigned short*)(smem + 25344);  // bufB: h1 (later sp overlay)
  unsigned short* Bm = Bh + 16*SW;
  unsigned short* Bl = Bm + 16*SW;
  float* sp  = (float*)(smem + 25344);
  float* sgt = (float*)(smem + 50688);
  unsigned short* Gh = (unsigned short*)(smem + 55040);
  unsigned short* Gm = Gh + 16*SG;
  unsigned short* Gl = Gm + 16*SG;
  __shared__ int sh_flag;
  const float* cnormp = (const float*)(pws + OCN);

  // ---- early long-latency loads (hidden under MLP) ----
  const float4 ksq = ((const float4*)ks)[(size_t)nw*(KK/4)+lane];
  int kv=0x7fffffff;
  if (isfinite(ksq.x)&&ksq.x>0.5f) kv=4*lane+0;
  if (isfinite(ksq.y)&&ksq.y>0.5f&&4*lane+1<kv) kv=4*lane+1;
  if (isfinite(ksq.z)&&ksq.z>0.5f&&4*lane+2<kv) kv=4*lane+2;
  if (isfinite(ksq.w)&&ksq.w>0.5f&&4*lane+3<kv) kv=4*lane+3;
  { unsigned long long bl=__ballot(kv!=0x7fffffff);
    if (bl){ int src=(int)__builtin_ctzll(bl); kv=__shfl(kv,src,64); } else kv=0; }
  const int kidx = kv;
  const float4 trq = ((const float4*)tr)[(size_t)nw*(KK*KK/4)+(size_t)kidx*(KK/4)+lane];
  const unsigned char mb = ((const unsigned char*)maskp)[nw];
  const uint32_t      mw32 = ((const uint32_t*)maskp)[nw];

  if (t==0) sh_flag = 0;
  __syncthreads();
  {
    const uint32_t* mwp = (const uint32_t*)maskp;
    uint32_t wd = mwp[t];
    if (wd!=0u && wd!=1u && wd!=0x3F800000u) atomicOr(&sh_flag,1);
  }

  // ---- stage layer-1 input with triple split ----
  for (int i=t; i<ROWS*DIN; i+=NT){
    int r=i/DIN, d=i%DIN; float v;
    if (d<DD){ v = z[(size_t)(n0+r)*DD+d]; if(!isfinite(v)) v=0.f; }
    else     { v = xt[(size_t)(n0+r)*DXX + (d-DD)]; }
    unsigned short h,m,l_; split3(v,h,m,l_);
    Ah[r*SW+d]=h; Am[r*SW+d]=m; Al[r*SW+d]=l_;
  }
  __syncthreads();
  const int flag = sh_flag;

  // ---- mfma GEMM layer: 1 ct/wave, 6 independent accumulators, depth-1 prefetch ----
  auto gemm_layer = [&](const unsigned short* Xh, const unsigned short* Xm, const unsigned short* Xl,
                        int KS, size_t wbase, const float* bias,
                        unsigned short* Yh, unsigned short* Ym, unsigned short* Yl){
    const int ct = wv;
    const size_t term = (size_t)16*KS*512;
    const float bb = bias[ct*16+lr];
    f32x4 ahh = {bb,bb,bb,bb};
    f32x4 ahm = {0.f,0.f,0.f,0.f}, amh=ahm, amm=ahm, alh=ahm, ahl=ahm;
    const int ar = lr*SW + lg*8;
    const unsigned short* p = &pws[wbase + ((size_t)ct*KS)*512 + (size_t)lane*8];
    short8 bh = *(const short8*)p, bm = *(const short8*)(p+term), bl = *(const short8*)(p+2*term);
    #pragma unroll 1
    for (int s=0; s<KS; ++s){
      short8 nbh, nbm, nbl;
      if (s+1<KS){
        const unsigned short* q = p + (size_t)(s+1)*512;
        nbh=*(const short8*)q; nbm=*(const short8*)(q+term); nbl=*(const short8*)(q+2*term);
      }
      short8 ah = *(const short8*)&Xh[ar + s*32];
      short8 am = *(const short8*)&Xm[ar + s*32];
      short8 al = *(const short8*)&Xl[ar + s*32];
      ahh=MFMA(ah,bh,ahh,0,0,0); ahm=MFMA(ah,bm,ahm,0,0,0);
      amh=MFMA(am,bh,amh,0,0,0); amm=MFMA(am,bm,amm,0,0,0);
      alh=MFMA(al,bh,alh,0,0,0); ahl=MFMA(ah,bl,ahl,0,0,0);
      bh=nbh; bm=nbm; bl=nbl;
    }
    #pragma unroll
    for (int j=0;j<4;++j){
      const int r = lg*4 + j;
      float h0 = tanhf(((ahh[j]+amh[j])+alh[j]) + ((ahm[j]+amm[j])+ahl[j]));
      unsigned short hh,hm,hl; split3(h0,hh,hm,hl);
      Yh[r*SW + ct*16+lr]=hh; Ym[r*SW + ct*16+lr]=hm; Yl[r*SW + ct*16+lr]=hl;
    }
  };

  gemm_layer(Ah,Am,Al, 6, OW1, b1, Bh,Bm,Bl);   // h1 -> bufB
  __syncthreads();
  gemm_layer(Bh,Bm,Bl, 8, OW2, b2, Ah,Am,Al);   // h2 -> bufA
  __syncthreads();

  // ---- MLP3: gt = h2 @ W3 + b3 (waves 0-3, one 16-col tile each) ----
  if (wv < 4){
    const int ct = wv;
    const size_t term = (size_t)4*8*512;
    const float bb = b3[ct*16+lr];
    f32x4 ahh = {bb,bb,bb,bb};
    f32x4 ahm = {0.f,0.f,0.f,0.f}, amh=ahm, amm=ahm, alh=ahm, ahl=ahm;
    const int ar = lr*SW + lg*8;
    const unsigned short* p = &pws[OW3 + ((size_t)ct*8)*512 + (size_t)lane*8];
    short8 bh = *(const short8*)p, bm = *(const short8*)(p+term), bl = *(const short8*)(p+2*term);
    #pragma unroll 1
    for (int s=0; s<8; ++s){
      short8 nbh, nbm, nbl;
      if (s+1<8){
        const unsigned short* q = p + (size_t)(s+1)*512;
        nbh=*(const short8*)q; nbm=*(const short8*)(q+term); nbl=*(const short8*)(q+2*term);
      }
      short8 ah = *(const short8*)&Ah[ar + s*32];
      short8 am = *(const short8*)&Am[ar + s*32];
      short8 al = *(const short8*)&Al[ar + s*32];
      ahh=MFMA(ah,bh,ahh,0,0,0); ahm=MFMA(ah,bm,ahm,0,0,0);
      amh=MFMA(am,bh,amh,0,0,0); amm=MFMA(am,bm,amm,0,0,0);
      alh=MFMA(al,bh,alh,0,0,0); ahl=MFMA(ah,bl,ahl,0,0,0);
      bh=nbh; bm=nbm; bl=nbl;
    }
    #pragma unroll
    for (int j=0;j<4;++j){
      const int r = lg*4 + j;
      float g = ((ahh[j]+amh[j])+alh[j]) + ((ahm[j]+amm[j])+ahl[j]);
      sgt[r*SSG + ct*16+lr] = g;
      unsigned short gh,gm,gl; split3(g,gh,gm,gl);
      Gh[r*SG + ct*16+lr]=gh; Gm[r*SG + ct*16+lr]=gm; Gl[r*SG + ct*16+lr]=gl;
    }
  }

  // ---- gumbel precompute (VALU, overlaps MLP3 on waves 4-15) ----
  uint32_t ka0,ka1;
  tf2x32(0u,(uint32_t)seedp[0],0u,0u,ka0,ka1);
  const bool m = flag ? (mb!=0) : (mw32!=0u);
  float g0=0,g1=0,g2=0,g3=0;
  if (!m){
    g0=gumbel_of(ka0,ka1,(uint32_t)(nw*KK+4*lane+0));
    g1=gumbel_of(ka0,ka1,(uint32_t)(nw*KK+4*lane+1));
    g2=gumbel_of(ka0,ka1,(uint32_t)(nw*KK+4*lane+2));
    g3=gumbel_of(ka0,ka1,(uint32_t)(nw*KK+4*lane+3));
  }
  __syncthreads();   // sgt/G ready; bufB (h1) dead -> sp overlay OK

  // ---- VQ scores via mfma: score[r][c] = ||C_c||^2 - 2 * (gt . C_c) ----
  {
    const int ct = wv;
    const size_t term = (size_t)16*2*512;
    f32x4 shh={0.f,0.f,0.f,0.f}, shm=shh, smh=shh, smm=shh, slh=shh, shl=shh;
    const int ar = lr*SG + lg*8;
    #pragma unroll
    for (int s=0; s<2; ++s){
      short8 ah = *(const short8*)&Gh[ar + s*32];
      short8 am = *(const short8*)&Gm[ar + s*32];
      short8 al = *(const short8*)&Gl[ar + s*32];
      const unsigned short* p = &pws[OCT + ((size_t)ct*2 + s)*512 + (size_t)lane*8];
      short8 bh=*(const short8*)p, bm=*(const short8*)(p+term), bl=*(const short8*)(p+2*term);
      shh=MFMA(ah,bh,shh,0,0,0); shm=MFMA(ah,bm,shm,0,0,0);
      smh=MFMA(am,bh,smh,0,0,0); smm=MFMA(am,bm,smm,0,0,0);
      slh=MFMA(al,bh,slh,0,0,0); shl=MFMA(ah,bl,shl,0,0,0);
    }
    const float cn = cnormp[ct*16+lr];
    #pragma unroll
    for (int j=0;j<4;++j){
      const int r = lg*4 + j;
      float dot = ((shh[j]+smh[j])+slh[j]) + ((shm[j]+smm[j])+shl[j]);
      sp[r*SSP + ct*16+lr] = cn - 2.f*dot;
    }
  }
  __syncthreads();

  // ---- wave-local finalize: wave wv owns row nw ----
  {
    const int n = nw, r = wv;
    const float FMX = 3.402823466e38f;
    float4 dq = *(const float4*)&sp[r*SSP + 4*lane];
    float dv=dq.x; int di=4*lane;
    if (dq.y<dv){dv=dq.y;di=4*lane+1;}
    if (dq.z<dv){dv=dq.z;di=4*lane+2;}
    if (dq.w<dv){dv=dq.w;di=4*lane+3;}
    #pragma unroll
    for (int mm=32;mm;mm>>=1){
      float ov=__shfl_xor(dv,mm,64); int oi=__shfl_xor(di,mm,64);
      if (ov<dv||(ov==dv&&oi<di)){dv=ov;di=oi;}
    }
    const int i1=di;
    float v0=(4*lane+0==i1)?FMX:dq.x, v1=(4*lane+1==i1)?FMX:dq.y;
    float v2=(4*lane+2==i1)?FMX:dq.z, v3=(4*lane+3==i1)?FMX:dq.w;
    float ev=v0; int ei=4*lane;
    if (v1<ev){ev=v1;ei=4*lane+1;}
    if (v2<ev){ev=v2;ei=4*lane+2;}
    if (v3<ev){ev=v3;ei=4*lane+3;}
    #pragma unroll
    for (int mm=32;mm;mm>>=1){
      float ov=__shfl_xor(ev,mm,64); int oi=__shfl_xor(ei,mm,64);
      if (ov<ev||(ov==ev&&oi<ei)){ev=ov;ei=oi;}
    }
    const int i2=ei;
    // exact fp32 recheck of top-2
    const float gd = sgt[r*SSG + lane];
    float e1 = gd - Cg[(size_t)i1*DD + lane];
    float e2 = gd - Cg[(size_t)i2*DD + lane];
    float s1 = e1*e1, s2 = e2*e2;
    #pragma unroll
    for (int mm=32;mm;mm>>=1){ s1 += __shfl_xor(s1,mm,64); s2 += __shfl_xor(s2,mm,64); }
    const float D1 = sqrtf(s1), D2 = sqrtf(s2);
    const int qk = (D2<D1 || (D2==D1 && i2<i1)) ? i2 : i1;

    // prior normalization
    float s=((trq.x+trq.y)+trq.z)+trq.w;
    #pragma unroll
    for (int mm=32;mm;mm>>=1) s+=__shfl_xor(s,mm,64);
    float q0=trq.x/s, q1=trq.y/s, q2=trq.z/s, q3=trq.w/s;
    { bool f0=isfinite(ksq.x),f1=isfinite(ksq.y),f2=isfinite(ksq.z),f3=isfinite(ksq.w);
      if (__any(!(f0&&f1&&f2&&f3))){
        float4 sq=((const float4*)spk)[(size_t)n*(KK/4)+lane];
        if(!f0)q0=sq.x; if(!f1)q1=sq.y; if(!f2)q2=sq.z; if(!f3)q3=sq.w;
      } }
    const float lp0=logf(q0), lp1=logf(q1), lp2=logf(q2), lp3=logf(q3);
    const int jq=qk&3;
    float lps=(jq==0)?lp0:((jq==1)?lp1:((jq==2)?lp2:lp3));
    const float logqk=__shfl(lps,qk>>2,64);

    int sel;
    if (m){ sel=qk; }
    else {
      float sc=g0+lp0; int si=4*lane;
      { float g=g1+lp1; if(g>sc){sc=g;si=4*lane+1;} }
      { float g=g2+lp2; if(g>sc){sc=g;si=4*lane+2;} }
      { float g=g3+lp3; if(g>sc){sc=g;si=4*lane+3;} }
      #pragma unroll
      for (int mm=32;mm;mm>>=1){
        float ov=__shfl_xor(sc,mm,64); int oi=__shfl_xor(si,mm,64);
        if (ov>sc||(ov==sc&&oi<si)){sc=ov;si=oi;}
      }
      sel=si;
    }

    ((float4*)out_qk)[(size_t)n*(KK/4)+lane]=make_float4(
      (4*lane+0==qk)?1.f:0.f,(4*lane+1==qk)?1.f:0.f,
      (4*lane+2==qk)?1.f:0.f,(4*lane+3==qk)?1.f:0.f);

    const float c=Cg[(size_t)sel*DD+lane];
    out_z[(size_t)n*DD+lane]=c;
    float df = sgt[r*SSG + lane] - c;
    float p=df*df;
    #pragma unroll
    for (int mm=32;mm;mm>>=1) p+=__shfl_xor(p,mm,64);
    if (lane==0){
      float tt=sqrtf(p);
      float dkl=-logqk;
      out_kl[n]=(tt+0.25f*tt)+dkl;
      out_dkl[n]=dkl;
    }
  }
}

extern "C" void kernel_launch(void* const* d_in, const int* in_sizes, int n_in,
                              void* d_out, int out_size, void* d_ws, size_t ws_size,
                              hipStream_t stream){
  const float* z    = (const float*)d_in[1];
  const float* ksm  = (const float*)d_in[2];
  const float* xt   = (const float*)d_in[3];
  const void*  mask = d_in[4];
  const float* tr   = (const float*)d_in[5];
  const float* spk  = (const float*)d_in[6];
  const float* W1   = (const float*)d_in[7];
  const float* b1   = (const float*)d_in[8];
  const float* W2   = (const float*)d_in[9];
  const float* b2   = (const float*)d_in[10];
  const float* W3   = (const float*)d_in[11];
  const float* b3   = (const float*)d_in[12];
  const float* C    = (const float*)d_in[13];
  const int*   seed = (const int*)d_in[14];

  float* out_z   = (float*)d_out;                // N*D
  float* out_kl  = out_z   + (size_t)NN*DD;      // N
  float* out_dkl = out_kl  + NN;                 // N
  float* out_qk  = out_dkl + NN;                 // N*K

  unsigned short* ws = (unsigned short*)d_ws;
  k_prep<<<73,256,0,stream>>>(W1, W2, W3, C, ws);
  k_fused<<<GRID,NT,0,stream>>>(z, ksm, xt, mask, tr, spk,
                                b1, b2, b3, C, seed, ws,
                                out_z, out_kl, out_dkl, out_qk);
}

// Round 16
// 30.821 us; speedup vs baseline: 1.0135x; 1.0135x over previous
//
#include <hip/hip_runtime.h>
#include <cstdint>
#include <cmath>

#define NN   4096
#define DXX  128
#define DD   64
#define KK   256
#define HH   256
#define DIN  192
#define ROWS 16
#define NT   1024
#define GRID (NN/ROWS)   // 256 blocks, 1 per CU, 16 waves -> 4 waves/SIMD

typedef __attribute__((ext_vector_type(8))) short short8;
typedef __attribute__((ext_vector_type(4))) float f32x4;
#define MFMA __builtin_amdgcn_mfma_f32_16x16x32_bf16

// ---- packed-weight offsets in d_ws (ushort units) ----
#define OW1 0          // 3 terms x 16ct x 6ks x 512
#define OW2 147456     // 3 x 16 x 8 x 512
#define OW3 344064     // 3 x 4  x 8 x 512
#define OCT 393216     // 3 x 16 x 2 x 512
#define OCN 442368     // 256 f32 (codebook row norms)

// ---- LDS strides ----
#define SW  264        // act row stride (ushorts)
#define SG  72         // gt-split row stride (ushorts)
#define SSP 260        // score row stride (floats)
#define SSG 68         // sgt row stride (floats)

__device__ __forceinline__ unsigned short f2bf(float x){
  uint32_t u = __float_as_uint(x);
  return (unsigned short)((u + 0x7fffu + ((u>>16)&1u)) >> 16);
}
__device__ __forceinline__ float bf2f(unsigned short b){
  return __uint_as_float(((uint32_t)b)<<16);
}
__device__ __forceinline__ void split3(float x, unsigned short& h, unsigned short& m, unsigned short& l){
  h = f2bf(x); float r1 = x - bf2f(h);
  m = f2bf(r1); float r2 = r1 - bf2f(m);
  l = f2bf(r2);
}

// ---------------- Threefry-2x32 (20 rounds), exact JAX semantics ----------------
__device__ __forceinline__ uint32_t rotl32(uint32_t v, uint32_t r){ return (v<<r)|(v>>(32u-r)); }
__device__ __forceinline__ void tf2x32(uint32_t k0, uint32_t k1,
                                       uint32_t x0, uint32_t x1,
                                       uint32_t& o0, uint32_t& o1){
  const uint32_t ks0=k0, ks1=k1, ks2 = k0 ^ k1 ^ 0x1BD11BDAu;
  x0 += ks0; x1 += ks1;
  x0+=x1; x1=rotl32(x1,13); x1^=x0;
  x0+=x1; x1=rotl32(x1,15); x1^=x0;
  x0+=x1; x1=rotl32(x1,26); x1^=x0;
  x0+=x1; x1=rotl32(x1, 6); x1^=x0;
  x0+=ks1; x1+=ks2+1u;
  x0+=x1; x1=rotl32(x1,17); x1^=x0;
  x0+=x1; x1=rotl32(x1,29); x1^=x0;
  x0+=x1; x1=rotl32(x1,16); x1^=x0;
  x0+=x1; x1=rotl32(x1,24); x1^=x0;
  x0+=ks2; x1+=ks0+2u;
  x0+=x1; x1=rotl32(x1,13); x1^=x0;
  x0+=x1; x1=rotl32(x1,15); x1^=x0;
  x0+=x1; x1=rotl32(x1,26); x1^=x0;
  x0+=x1; x1=rotl32(x1, 6); x1^=x0;
  x0+=ks0; x1+=ks1+3u;
  x0+=x1; x1=rotl32(x1,17); x1^=x0;
  x0+=x1; x1=rotl32(x1,29); x1^=x0;
  x0+=x1; x1=rotl32(x1,16); x1^=x0;
  x0+=x1; x1=rotl32(x1,24); x1^=x0;
  x0+=ks1; x1+=ks2+4u;
  x0+=x1; x1=rotl32(x1,13); x1^=x0;
  x0+=x1; x1=rotl32(x1,15); x1^=x0;
  x0+=x1; x1=rotl32(x1,26); x1^=x0;
  x0+=x1; x1=rotl32(x1, 6); x1^=x0;
  x0+=ks2; x1+=ks0+5u;
  o0=x0; o1=x1;
}
__device__ __forceinline__ float gumbel_of(uint32_t ka0, uint32_t ka1, uint32_t idx){
  uint32_t o0,o1; tf2x32(ka0,ka1,0u,idx,o0,o1);
  const uint32_t bits = o0 ^ o1;
  const float TINY = 1.17549435e-38f;
  const float f = __uint_as_float((bits>>9) | 0x3F800000u) - 1.0f;
  const float u = fmaxf(TINY, f + TINY);
  return -logf(-logf(u));
}

// ---------------- prep v3: 73 fine blocks; coalesced -> LDS -> short8 ----------------
__global__ __launch_bounds__(256) void k_prep(const float* __restrict__ W1,
    const float* __restrict__ W2, const float* __restrict__ W3,
    const float* __restrict__ Cg, unsigned short* __restrict__ ws){
  const int b = blockIdx.x, t = threadIdx.x;
  __shared__ __align__(16) float lds[2112];
  if (b < 64){
    const float* W; int N, KS, NTt, ks, cg; size_t base;
    if (b < 24){ W=W1; N=256; KS=6; NTt=16; base=OW1; ks=b/4;      cg=b&3; }
    else if (b < 56){ W=W2; N=256; KS=8; NTt=16; base=OW2; ks=(b-24)/4; cg=(b-24)&3; }
    else { W=W3; N=64; KS=8; NTt=4; base=OW3; ks=b-56; cg=0; }
    const int k0 = ks*32, cb = cg*64;
    for (int idx=t; idx<512; idx+=256){
      int row = idx>>4, c4 = idx&15;
      float4 v = *(const float4*)&W[(size_t)(k0+row)*N + cb + c4*4];
      float* d = &lds[row*65 + c4*4];
      d[0]=v.x; d[1]=v.y; d[2]=v.z; d[3]=v.w;
    }
    __syncthreads();
    const size_t term = (size_t)NTt*KS*512;
    const int lane = t&63, ctl = t>>6;
    const int ct = cg*4 + ctl;
    const int cl = ctl*16 + (lane&15);
    const int kofs = 8*(lane>>4);
    short8 hv,mv,lv;
    #pragma unroll
    for (int j=0;j<8;++j){
      float w = lds[(kofs+j)*65 + cl];
      unsigned short h,m,lo; split3(w,h,m,lo);
      hv[j]=(short)h; mv[j]=(short)m; lv[j]=(short)lo;
    }
    const size_t o = base + ((size_t)ct*KS+ks)*512 + (size_t)lane*8;
    *(short8*)&ws[o]=hv; *(short8*)&ws[o+term]=mv; *(short8*)&ws[o+2*term]=lv;
  } else if (b < 72){
    const int ks = (b-64)/4, cg = (b-64)&3;
    const int d0 = ks*32, code0 = cg*64;
    for (int idx=t; idx<512; idx+=256){
      int code = idx>>3, d4 = idx&7;
      float4 v = *(const float4*)&Cg[(size_t)(code0+code)*64 + d0 + d4*4];
      float* d = &lds[code*33 + d4*4];
      d[0]=v.x; d[1]=v.y; d[2]=v.z; d[3]=v.w;
    }
    __syncthreads();
    const size_t term = (size_t)16*2*512;
    const int lane = t&63, ctl = t>>6;
    const int ct = cg*4 + ctl;
    const int cl = ctl*16 + (lane&15);
    const int kofs = 8*(lane>>4);
    short8 hv,mv,lv;
    #pragma unroll
    for (int j=0;j<8;++j){
      float w = lds[cl*33 + kofs + j];
      unsigned short h,m,lo; split3(w,h,m,lo);
      hv[j]=(short)h; mv[j]=(short)m; lv[j]=(short)lo;
    }
    const size_t o = OCT + ((size_t)ct*2+ks)*512 + (size_t)lane*8;
    *(short8*)&ws[o]=hv; *(short8*)&ws[o+term]=mv; *(short8*)&ws[o+2*term]=lv;
  } else {
    const int c = t;
    float s=0.f;
    #pragma unroll 8
    for (int d=0; d<64; ++d){ float v=Cg[(size_t)c*64+d]; s += v*v; }
    ((float*)(ws+OCN))[c] = s;
  }
}

// ---------------- fused main kernel ----------------
__global__ __launch_bounds__(NT,4) void k_fused(
    const float* __restrict__ z, const float* __restrict__ ks,
    const float* __restrict__ xt, const void* __restrict__ maskp,
    const float* __restrict__ tr, const float* __restrict__ spk,
    const float* __restrict__ b1, const float* __restrict__ b2,
    const float* __restrict__ b3, const float* __restrict__ Cg,
    const int* __restrict__ seedp, const unsigned short* __restrict__ pws,
    float* __restrict__ out_z, float* __restrict__ out_kl,
    float* __restrict__ out_dkl, float* __restrict__ out_qk)
{
  const int t    = threadIdx.x;
  const int lane = t & 63;
  const int wv   = t >> 6;            // wave 0..15
  const int lr   = lane & 15;
  const int lg   = lane >> 4;
  const int n0   = blockIdx.x * ROWS;
  const int nw   = n0 + wv;

  __shared__ __align__(16) char smem[61952];
  unsigned short* Ah = (unsigned short*)smem;            // bufA: layer input / h2
  unsigned short* Am = Ah + 16*SW;
  unsigned short* Al = Am + 16*SW;
  unsigned short* Bh = (unsigned short*)(smem + 25344);  // bufB: h1 (later part/sp)
  unsigned short* Bm = Bh + 16*SW;
  unsigned short* Bl = Bm + 16*SW;
  float* part = (float*)(smem + 25344);                  // MLP3 partials [4][16][65]
  float* sp   = (float*)(smem + 25344);                  // VQ scores overlay
  float* sgt  = (float*)(smem + 50688);
  unsigned short* Gh = (unsigned short*)(smem + 55040);
  unsigned short* Gm = Gh + 16*SG;
  unsigned short* Gl = Gm + 16*SG;
  __shared__ int sh_flag;
  const float* cnormp = (const float*)(pws + OCN);

  // ---- early long-latency loads (hidden under staging/MLP) ----
  const float4 ksq = ((const float4*)ks)[(size_t)nw*(KK/4)+lane];
  int kv=0x7fffffff;
  if (isfinite(ksq.x)&&ksq.x>0.5f) kv=4*lane+0;
  if (isfinite(ksq.y)&&ksq.y>0.5f&&4*lane+1<kv) kv=4*lane+1;
  if (isfinite(ksq.z)&&ksq.z>0.5f&&4*lane+2<kv) kv=4*lane+2;
  if (isfinite(ksq.w)&&ksq.w>0.5f&&4*lane+3<kv) kv=4*lane+3;
  { unsigned long long bl=__ballot(kv!=0x7fffffff);
    if (bl){ int src=(int)__builtin_ctzll(bl); kv=__shfl(kv,src,64); } else kv=0; }
  const int kidx = kv;
  const float4 trq = ((const float4*)tr)[(size_t)nw*(KK*KK/4)+(size_t)kidx*(KK/4)+lane];
  const unsigned char mb = ((const unsigned char*)maskp)[nw];
  const uint32_t      mw32 = ((const uint32_t*)maskp)[nw];

  // ---- MLP1 first-fragment prefetch (independent of LDS staging) ----
  const size_t term1 = (size_t)16*6*512;
  const unsigned short* p1 = &pws[OW1 + ((size_t)wv*6)*512 + (size_t)lane*8];
  short8 f1h = *(const short8*)p1, f1m = *(const short8*)(p1+term1), f1l = *(const short8*)(p1+2*term1);

  if (t==0) sh_flag = 0;
  __syncthreads();
  {
    const uint32_t* mwp = (const uint32_t*)maskp;
    uint32_t wd = mwp[t];
    if (wd!=0u && wd!=1u && wd!=0x3F800000u) atomicOr(&sh_flag,1);
  }

  // ---- stage layer-1 input with triple split ----
  for (int i=t; i<ROWS*DIN; i+=NT){
    int r=i/DIN, d=i%DIN; float v;
    if (d<DD){ v = z[(size_t)(n0+r)*DD+d]; if(!isfinite(v)) v=0.f; }
    else     { v = xt[(size_t)(n0+r)*DXX + (d-DD)]; }
    unsigned short h,m,l_; split3(v,h,m,l_);
    Ah[r*SW+d]=h; Am[r*SW+d]=m; Al[r*SW+d]=l_;
  }
  __syncthreads();
  const int flag = sh_flag;

  // ---- mfma GEMM layer: 1 ct/wave, 2-chain acc, preloaded first frag ----
  auto gemm_layer = [&](const unsigned short* Xh, const unsigned short* Xm, const unsigned short* Xl,
                        int KS, size_t wbase, const float* bias,
                        short8 bh, short8 bm, short8 bl,
                        unsigned short* Yh, unsigned short* Ym, unsigned short* Yl){
    const int ct = wv;
    const size_t term = (size_t)16*KS*512;
    const float bb = bias[ct*16+lr];
    f32x4 a0 = {bb,bb,bb,bb}, a1 = {0.f,0.f,0.f,0.f};
    const int ar = lr*SW + lg*8;
    const unsigned short* p = &pws[wbase + ((size_t)ct*KS)*512 + (size_t)lane*8];
    #pragma unroll 1
    for (int s=0; s<KS; ++s){
      short8 nbh, nbm, nbl;
      if (s+1<KS){
        const unsigned short* q = p + (size_t)(s+1)*512;
        nbh=*(const short8*)q; nbm=*(const short8*)(q+term); nbl=*(const short8*)(q+2*term);
      }
      short8 ah = *(const short8*)&Xh[ar + s*32];
      short8 am = *(const short8*)&Xm[ar + s*32];
      short8 al = *(const short8*)&Xl[ar + s*32];
      a0=MFMA(ah,bh,a0,0,0,0); a1=MFMA(ah,bm,a1,0,0,0);
      a0=MFMA(am,bh,a0,0,0,0); a1=MFMA(am,bm,a1,0,0,0);
      a0=MFMA(al,bh,a0,0,0,0); a1=MFMA(ah,bl,a1,0,0,0);
      bh=nbh; bm=nbm; bl=nbl;
    }
    #pragma unroll
    for (int j=0;j<4;++j){
      const int r = lg*4 + j;
      float h0 = tanhf(a0[j]+a1[j]);
      unsigned short hh,hm,hl; split3(h0,hh,hm,hl);
      Yh[r*SW + ct*16+lr]=hh; Ym[r*SW + ct*16+lr]=hm; Yl[r*SW + ct*16+lr]=hl;
    }
  };

  // ---- MLP1 ----
  gemm_layer(Ah,Am,Al, 6, OW1, b1, f1h,f1m,f1l, Bh,Bm,Bl);
  // prefetch MLP2 first frag before barrier
  const size_t term2 = (size_t)16*8*512;
  const unsigned short* p2 = &pws[OW2 + ((size_t)wv*8)*512 + (size_t)lane*8];
  short8 f2h = *(const short8*)p2, f2m = *(const short8*)(p2+term2), f2l = *(const short8*)(p2+2*term2);
  __syncthreads();

  // ---- MLP2 ----
  gemm_layer(Bh,Bm,Bl, 8, OW2, b2, f2h,f2m,f2l, Ah,Am,Al);
  // prefetch MLP3 first frag (new mapping: ct=wv&3, kq=wv>>2, step kq*2)
  const int ct3 = wv & 3, kq3 = wv >> 2;
  const size_t term3 = (size_t)4*8*512;
  const unsigned short* p3 = &pws[OW3 + ((size_t)ct3*8 + kq3*2)*512 + (size_t)lane*8];
  short8 f3h = *(const short8*)p3, f3m = *(const short8*)(p3+term3), f3l = *(const short8*)(p3+2*term3);
  __syncthreads();

  // ---- MLP3: 4-way K-split across ALL 16 waves, partials to LDS ----
  {
    f32x4 a0 = {0.f,0.f,0.f,0.f}, a1 = a0;
    const int ar = lr*SW + lg*8;
    short8 bh=f3h, bm=f3m, bl=f3l;
    #pragma unroll 1
    for (int s=0; s<2; ++s){
      short8 nbh, nbm, nbl;
      if (s==0){
        const unsigned short* q = p3 + 512;
        nbh=*(const short8*)q; nbm=*(const short8*)(q+term3); nbl=*(const short8*)(q+2*term3);
      }
      const int sg = kq3*2 + s;
      short8 ah = *(const short8*)&Ah[ar + sg*32];
      short8 am = *(const short8*)&Am[ar + sg*32];
      short8 al = *(const short8*)&Al[ar + sg*32];
      a0=MFMA(ah,bh,a0,0,0,0); a1=MFMA(ah,bm,a1,0,0,0);
      a0=MFMA(am,bh,a0,0,0,0); a1=MFMA(am,bm,a1,0,0,0);
      a0=MFMA(al,bh,a0,0,0,0); a1=MFMA(ah,bl,a1,0,0,0);
      bh=nbh; bm=nbm; bl=nbl;
    }
    #pragma unroll
    for (int j=0;j<4;++j){
      const int r = lg*4 + j;
      part[kq3*1040 + r*65 + ct3*16+lr] = a0[j]+a1[j];
    }
  }

  // ---- gumbel (independent; overlaps partial-barrier wait) ----
  uint32_t ka0,ka1;
  tf2x32(0u,(uint32_t)seedp[0],0u,0u,ka0,ka1);
  const bool m = flag ? (mb!=0) : (mw32!=0u);
  float g0=0,g1=0,g2=0,g3=0;
  if (!m){
    g0=gumbel_of(ka0,ka1,(uint32_t)(nw*KK+4*lane+0));
    g1=gumbel_of(ka0,ka1,(uint32_t)(nw*KK+4*lane+1));
    g2=gumbel_of(ka0,ka1,(uint32_t)(nw*KK+4*lane+2));
    g3=gumbel_of(ka0,ka1,(uint32_t)(nw*KK+4*lane+3));
  }
  __syncthreads();   // partials ready

  // ---- combine partials -> gt (+ splits); 1 value/thread ----
  {
    const int r = t>>6, c = t&63;
    float g = b3[c];
    g += part[0*1040 + r*65 + c];
    g += part[1*1040 + r*65 + c];
    g += part[2*1040 + r*65 + c];
    g += part[3*1040 + r*65 + c];
    sgt[r*SSG + c] = g;
    unsigned short gh,gm,gl; split3(g,gh,gm,gl);
    Gh[r*SG+c]=gh; Gm[r*SG+c]=gm; Gl[r*SG+c]=gl;
  }
  // prefetch VQ first frag before barrier
  const size_t termC = (size_t)16*2*512;
  const unsigned short* pC = &pws[OCT + ((size_t)wv*2)*512 + (size_t)lane*8];
  short8 fCh = *(const short8*)pC, fCm = *(const short8*)(pC+termC), fCl = *(const short8*)(pC+2*termC);
  __syncthreads();   // sgt/G ready; part region reusable as sp

  // ---- VQ scores via mfma: score[r][c] = ||C_c||^2 - 2 * (gt . C_c) ----
  {
    const int ct = wv;
    f32x4 s0={0.f,0.f,0.f,0.f}, s1=s0;
    const int ar = lr*SG + lg*8;
    short8 bh=fCh, bm=fCm, bl=fCl;
    #pragma unroll 1
    for (int s=0; s<2; ++s){
      short8 nbh, nbm, nbl;
      if (s==0){
        const unsigned short* q = pC + 512;
        nbh=*(const short8*)q; nbm=*(const short8*)(q+termC); nbl=*(const short8*)(q+2*termC);
      }
      short8 ah = *(const short8*)&Gh[ar + s*32];
      short8 am = *(const short8*)&Gm[ar + s*32];
      short8 al = *(const short8*)&Gl[ar + s*32];
      s0=MFMA(ah,bh,s0,0,0,0); s1=MFMA(ah,bm,s1,0,0,0);
      s0=MFMA(am,bh,s0,0,0,0); s1=MFMA(am,bm,s1,0,0,0);
      s0=MFMA(al,bh,s0,0,0,0); s1=MFMA(ah,bl,s1,0,0,0);
      bh=nbh; bm=nbm; bl=nbl;
    }
    const float cn = cnormp[ct*16+lr];
    #pragma unroll
    for (int j=0;j<4;++j){
      const int r = lg*4 + j;
      sp[r*SSP + ct*16+lr] = cn - 2.f*(s0[j]+s1[j]);
    }
  }
  __syncthreads();

  // ---- wave-local finalize: wave wv owns row nw ----
  {
    const int n = nw, r = wv;
    const float FMX = 3.402823466e38f;
    float4 dq = *(const float4*)&sp[r*SSP + 4*lane];
    float dv=dq.x; int di=4*lane;
    if (dq.y<dv){dv=dq.y;di=4*lane+1;}
    if (dq.z<dv){dv=dq.z;di=4*lane+2;}
    if (dq.w<dv){dv=dq.w;di=4*lane+3;}
    #pragma unroll
    for (int mm=32;mm;mm>>=1){
      float ov=__shfl_xor(dv,mm,64); int oi=__shfl_xor(di,mm,64);
      if (ov<dv||(ov==dv&&oi<di)){dv=ov;di=oi;}
    }
    const int i1=di;
    float v0=(4*lane+0==i1)?FMX:dq.x, v1=(4*lane+1==i1)?FMX:dq.y;
    float v2=(4*lane+2==i1)?FMX:dq.z, v3=(4*lane+3==i1)?FMX:dq.w;
    float ev=v0; int ei=4*lane;
    if (v1<ev){ev=v1;ei=4*lane+1;}
    if (v2<ev){ev=v2;ei=4*lane+2;}
    if (v3<ev){ev=v3;ei=4*lane+3;}
    #pragma unroll
    for (int mm=32;mm;mm>>=1){
      float ov=__shfl_xor(ev,mm,64); int oi=__shfl_xor(ei,mm,64);
      if (ov<ev||(ov==ev&&oi<ei)){ev=ov;ei=oi;}
    }
    const int i2=ei;
    // exact fp32 recheck of top-2
    const float gd = sgt[r*SSG + lane];
    float e1 = gd - Cg[(size_t)i1*DD + lane];
    float e2 = gd - Cg[(size_t)i2*DD + lane];
    float s1 = e1*e1, s2 = e2*e2;
    #pragma unroll
    for (int mm=32;mm;mm>>=1){ s1 += __shfl_xor(s1,mm,64); s2 += __shfl_xor(s2,mm,64); }
    const float D1 = sqrtf(s1), D2 = sqrtf(s2);
    const int qk = (D2<D1 || (D2==D1 && i2<i1)) ? i2 : i1;

    // prior normalization
    float s=((trq.x+trq.y)+trq.z)+trq.w;
    #pragma unroll
    for (int mm=32;mm;mm>>=1) s+=__shfl_xor(s,mm,64);
    float q0=trq.x/s, q1=trq.y/s, q2=trq.z/s, q3=trq.w/s;
    { bool f0=isfinite(ksq.x),f1=isfinite(ksq.y),f2=isfinite(ksq.z),f3=isfinite(ksq.w);
      if (__any(!(f0&&f1&&f2&&f3))){
        float4 sq=((const float4*)spk)[(size_t)n*(KK/4)+lane];
        if(!f0)q0=sq.x; if(!f1)q1=sq.y; if(!f2)q2=sq.z; if(!f3)q3=sq.w;
      } }
    const float lp0=logf(q0), lp1=logf(q1), lp2=logf(q2), lp3=logf(q3);
    const int jq=qk&3;
    float lps=(jq==0)?lp0:((jq==1)?lp1:((jq==2)?lp2:lp3));
    const float logqk=__shfl(lps,qk>>2,64);

    int sel;
    if (m){ sel=qk; }
    else {
      float sc=g0+lp0; int si=4*lane;
      { float g=g1+lp1; if(g>sc){sc=g;si=4*lane+1;} }
      { float g=g2+lp2; if(g>sc){sc=g;si=4*lane+2;} }
      { float g=g3+lp3; if(g>sc){sc=g;si=4*lane+3;} }
      #pragma unroll
      for (int mm=32;mm;mm>>=1){
        float ov=__shfl_xor(sc,mm,64); int oi=__shfl_xor(si,mm,64);
        if (ov>sc||(ov==sc&&oi<si)){sc=ov;si=oi;}
      }
      sel=si;
    }

    ((float4*)out_qk)[(size_t)n*(KK/4)+lane]=make_float4(
      (4*lane+0==qk)?1.f:0.f,(4*lane+1==qk)?1.f:0.f,
      (4*lane+2==qk)?1.f:0.f,(4*lane+3==qk)?1.f:0.f);

    const float c=Cg[(size_t)sel*DD+lane];
    out_z[(size_t)n*DD+lane]=c;
    float df = sgt[r*SSG + lane] - c;
    float p=df*df;
    #pragma unroll
    for (int mm=32;mm;mm>>=1) p+=__shfl_xor(p,mm,64);
    if (lane==0){
      float tt=sqrtf(p);
      float dkl=-logqk;
      out_kl[n]=(tt+0.25f*tt)+dkl;
      out_dkl[n]=dkl;
    }
  }
}

extern "C" void kernel_launch(void* const* d_in, const int* in_sizes, int n_in,
                              void* d_out, int out_size, void* d_ws, size_t ws_size,
                              hipStream_t stream){
  const float* z    = (const float*)d_in[1];
  const float* ksm  = (const float*)d_in[2];
  const float* xt   = (const float*)d_in[3];
  const void*  mask = d_in[4];
  const float* tr   = (const float*)d_in[5];
  const float* spk  = (const float*)d_in[6];
  const float* W1   = (const float*)d_in[7];
  const float* b1   = (const float*)d_in[8];
  const float* W2   = (const float*)d_in[9];
  const float* b2   = (const float*)d_in[10];
  const float* W3   = (const float*)d_in[11];
  const float* b3   = (const float*)d_in[12];
  const float* C    = (const float*)d_in[13];
  const int*   seed = (const int*)d_in[14];

  float* out_z   = (float*)d_out;                // N*D
  float* out_kl  = out_z   + (size_t)NN*DD;      // N
  float* out_dkl = out_kl  + NN;                 // N
  float* out_qk  = out_dkl + NN;                 // N*K

  unsigned short* ws = (unsigned short*)d_ws;
  k_prep<<<73,256,0,stream>>>(W1, W2, W3, C, ws);
  k_fused<<<GRID,NT,0,stream>>>(z, ksm, xt, mask, tr, spk,
                                b1, b2, b3, C, seed, ws,
                                out_z, out_kl, out_dkl, out_qk);
}